// Round 9
// baseline (299.464 us; speedup 1.0000x reference)
//
#include <hip/hip_runtime.h>
#include <hip/hip_bf16.h>

#define N_NODES 20000
#define B 4
#define H 128
#define I_DIM 64
#define E_MAX 320000
#define CAP 64              // padded CSR row capacity (in-deg ~Poisson(16); P(>63) ~ e^-40)

typedef __attribute__((ext_vector_type(8))) short short8;   // 8 bf16 = 4 VGPR (MFMA A/B frag)
typedef __attribute__((ext_vector_type(4))) float float4v;  // MFMA C/D frag

// ---- all scratch in module-static device globals (no d_ws dependence) ----
// g_cnt_dst / g_deg_src zeroed by fused_kernel (own-nodes only, end of kernel).
__device__ int   g_cnt_dst[N_NODES];        // atomic cursor == final in-degree
__device__ int   g_deg_src[N_NODES];        // out-degree
__device__ int   g_csr[N_NODES * CAP];      // padded CSR: row n at n*CAP
__device__ __align__(16) float g_xg[4 * B * H];   // layout: [(b*H+h)*4 + gate]
// batch-interleaved bf16 h_prev, PRE-SCALED by dn_src: g_hs[n*H+h]={bf16 h*dn, b=0..3}
__device__ __align__(16) uint2 g_hs[N_NODES * H];
// Wg as bf16 in MFMA B-fragment order: idx=((tn*4+kb)*64+lane)*8+j holds
// Wg[kb*32+(lane>>4)*8+j][tn*16+(lane&15)]  -> per-frag load = 1 coalesced dwordx4
__device__ __align__(16) unsigned short g_wgB[H * H];

// ---- K1: src-degree histogram + xgate + Wg bf16 B-frag pack ----
__global__ __launch_bounds__(256)
void degree_kernel(const int* __restrict__ src, int E, int eb,
                   const float* __restrict__ x,
                   const float* __restrict__ Wi, const float* __restrict__ bi,
                   const float* __restrict__ Wf, const float* __restrict__ bf_,
                   const float* __restrict__ Wo, const float* __restrict__ bo,
                   const float* __restrict__ Wc, const float* __restrict__ bc,
                   const float* __restrict__ Wg) {
    int blk = blockIdx.x;
    int t = threadIdx.x;
    if (blk < eb) {
        int e = blk * 256 + t;
        if (e < E) atomicAdd(&g_deg_src[src[e]], 1);
    } else if (blk < eb + 8) {
        int bid = blk - eb;                       // 0..7
        int g = bid >> 1;                         // gate 0..3
        int b = ((bid & 1) << 1) | (t >> 7);      // batch 0..3
        int h = t & 127;
        const float* W;
        const float* bb;
        switch (g) {
            case 0: W = Wi; bb = bi; break;
            case 1: W = Wf; bb = bf_; break;
            case 2: W = Wo; bb = bo; break;
            default: W = Wc; bb = bc; break;
        }
        float acc = bb[h];
#pragma unroll
        for (int i = 0; i < I_DIM; i++)
            acc += x[b * I_DIM + i] * W[i * H + h];
        g_xg[(b * H + h) * 4 + g] = acc;          // gate-innermost for float4 read
    } else {
        // B-fragment pack: 64 blocks x 256 threads = 16384 = H*H elements
        int i = (blk - eb - 8) * 256 + t;
        int tn = i >> 11;
        int rem = i & 2047;
        int kb = rem >> 9;
        int rem2 = rem & 511;
        int lane = rem2 >> 3;
        int j = rem2 & 7;
        int k  = kb * 32 + (lane >> 4) * 8 + j;
        int nn = tn * 16 + (lane & 15);
        __hip_bfloat16 hv = __float2bfloat16(Wg[k * H + nn]);
        g_wgB[i] = *reinterpret_cast<unsigned short*>(&hv);
    }
}

// ---- K2: pack (dn_src folded into bf16) + padded-CSR place ----
__global__ __launch_bounds__(256)
void mid_kernel(const float* __restrict__ h_prev,
                const int* __restrict__ src, const int* __restrict__ dst, int E) {
    const int PACK_BLKS = (N_NODES * H) / 256;   // 10000, exact
    int blk = blockIdx.x;
    int t = threadIdx.x;

    if (blk < PACK_BLKS) {
        int i = blk * 256 + t;                    // (n*H + h)
        int n = i >> 7;                           // H = 128
        float sc = rsqrtf(fmaxf((float)g_deg_src[n], 1.0f));
        const long stride = (long)N_NODES * H;
        float v0 = h_prev[i] * sc;
        float v1 = h_prev[i + stride] * sc;
        float v2 = h_prev[i + 2 * stride] * sc;
        float v3 = h_prev[i + 3 * stride] * sc;
        __hip_bfloat162 p01 = __float22bfloat162_rn(make_float2(v0, v1));
        __hip_bfloat162 p23 = __float22bfloat162_rn(make_float2(v2, v3));
        uint2 wv;
        wv.x = *reinterpret_cast<unsigned int*>(&p01);
        wv.y = *reinterpret_cast<unsigned int*>(&p23);
        g_hs[i] = wv;
    } else {
        int e = (blk - PACK_BLKS) * 256 + t;
        if (e < E) {
            int d = dst[e];
            int slot = atomicAdd(&g_cnt_dst[d], 1);
            if (slot < CAP) g_csr[(d << 6) + slot] = src[e];
        }
    }
}

__device__ __forceinline__ float fast_sigmoid(float z) {
    return 1.f / (1.f + __expf(-z));
}
__device__ __forceinline__ float fast_tanh(float z) {
    return 1.f - 2.f / (__expf(2.f * z) + 1.f);
}
__device__ __forceinline__ unsigned pack2bf(float lo, float hi) {
    __hip_bfloat162 p = __float22bfloat162_rn(make_float2(lo, hi));
    return *reinterpret_cast<unsigned*>(&p);
}

// ------- K3 fused: wave-independent, 2 nodes/wave, lean registers. ----------
// Per wave: gather node0+node1 (independent accumulators -> cross-node ILP),
// pack 8-row A-tile (rows 8-15 zero via exec-masked frag load), then two
// 4-N-tile MFMA halves, each followed immediately by its epilogue (c[4] live
// = 16 regs; half0's c_prev loads overlap half1's MFMAs). No __syncthreads.
// C decode: col=lane&15 -> h-in-tile; row=(lane>>4)*4+jj -> node=lane>>4 (<2),
// batch=jj  => epilogue active on lanes 0..31.
__global__ __launch_bounds__(256)
void fused_kernel(const float* __restrict__ bg,
                  const float* __restrict__ c_prev,
                  float* __restrict__ out_h, float* __restrict__ out_c) {
    int t = threadIdx.x;
    int w = t >> 6;
    int lane = t & 63;
    int q0 = (blockIdx.x * 4 + w) * 2;         // first of this wave's 2 nodes
    const long stride = (long)N_NODES * H;

    __shared__ int            sbase[4][2 * 64];      // wave-private row bases
    __shared__ unsigned short Atile[4][16][136];     // wave-private A-tile

    int cnt0 = g_cnt_dst[q0];
    int cnt1 = g_cnt_dst[q0 + 1];
    float dd0 = rsqrtf(fmaxf((float)cnt0, 1.0f)); if (cnt0 > CAP) cnt0 = CAP;
    float dd1 = rsqrtf(fmaxf((float)cnt1, 1.0f)); if (cnt1 > CAP) cnt1 = CAP;

    // stage both nodes' row bases (2 coalesced loads)
    {
        int s0 = g_csr[(q0 << 6) + (lane < cnt0 ? lane : 0)];
        int s1 = g_csr[((q0 + 1) << 6) + (lane < cnt1 ? lane : 0)];
        sbase[w][lane]      = s0 << 6;         // uint4-unit row base
        sbase[w][64 + lane] = s1 << 6;
    }

    const uint4* hs4 = reinterpret_cast<const uint4*>(g_hs);
    const int* sb = sbase[w];

#define ACCV(v) { \
        __hip_bfloat162 p; float2 f; \
        p = *reinterpret_cast<__hip_bfloat162*>(&(v).x); f = __bfloat1622float2(p); a0 += f.x; a1 += f.y; \
        p = *reinterpret_cast<__hip_bfloat162*>(&(v).y); f = __bfloat1622float2(p); a2 += f.x; a3 += f.y; \
        p = *reinterpret_cast<__hip_bfloat162*>(&(v).z); f = __bfloat1622float2(p); a4 += f.x; a5 += f.y; \
        p = *reinterpret_cast<__hip_bfloat162*>(&(v).w); f = __bfloat1622float2(p); a6 += f.x; a7 += f.y; }

#define GATHER_NODE(i, cnt, dd) { \
        float a0 = 0.f, a1 = 0.f, a2 = 0.f, a3 = 0.f; \
        float a4 = 0.f, a5 = 0.f, a6 = 0.f, a7 = 0.f; \
        int j = 0; \
        for (; j + 8 <= (cnt); j += 8) { \
            int b0 = sb[(i) * 64 + j];     int b1 = sb[(i) * 64 + j + 1]; \
            int b2 = sb[(i) * 64 + j + 2]; int b3 = sb[(i) * 64 + j + 3]; \
            int b4 = sb[(i) * 64 + j + 4]; int b5 = sb[(i) * 64 + j + 5]; \
            int b6 = sb[(i) * 64 + j + 6]; int b7 = sb[(i) * 64 + j + 7]; \
            uint4 v0 = hs4[b0 + lane]; uint4 v1 = hs4[b1 + lane]; \
            uint4 v2 = hs4[b2 + lane]; uint4 v3 = hs4[b3 + lane]; \
            uint4 v4 = hs4[b4 + lane]; uint4 v5 = hs4[b5 + lane]; \
            uint4 v6 = hs4[b6 + lane]; uint4 v7 = hs4[b7 + lane]; \
            ACCV(v0); ACCV(v1); ACCV(v2); ACCV(v3); \
            ACCV(v4); ACCV(v5); ACCV(v6); ACCV(v7); \
        } \
        for (; j + 4 <= (cnt); j += 4) { \
            int b0 = sb[(i) * 64 + j];     int b1 = sb[(i) * 64 + j + 1]; \
            int b2 = sb[(i) * 64 + j + 2]; int b3 = sb[(i) * 64 + j + 3]; \
            uint4 v0 = hs4[b0 + lane]; uint4 v1 = hs4[b1 + lane]; \
            uint4 v2 = hs4[b2 + lane]; uint4 v3 = hs4[b3 + lane]; \
            ACCV(v0); ACCV(v1); ACCV(v2); ACCV(v3); \
        } \
        for (; j < (cnt); j++) { \
            uint4 v = hs4[sb[(i) * 64 + j] + lane]; \
            ACCV(v); \
        } \
        *reinterpret_cast<unsigned*>(&Atile[w][(i) * 4 + 0][2 * lane]) = pack2bf(a0 * (dd), a4 * (dd)); \
        *reinterpret_cast<unsigned*>(&Atile[w][(i) * 4 + 1][2 * lane]) = pack2bf(a1 * (dd), a5 * (dd)); \
        *reinterpret_cast<unsigned*>(&Atile[w][(i) * 4 + 2][2 * lane]) = pack2bf(a2 * (dd), a6 * (dd)); \
        *reinterpret_cast<unsigned*>(&Atile[w][(i) * 4 + 3][2 * lane]) = pack2bf(a3 * (dd), a7 * (dd)); \
    }

    GATHER_NODE(0, cnt0, dd0);
    GATHER_NODE(1, cnt1, dd1);
#undef GATHER_NODE
#undef ACCV

    // ---- MFMA + epilogue in two 4-N-tile halves (c[4] live = 16 regs) ----
    int arow = lane & 15;
    int agrp = lane >> 4;
    int hl = lane & 15;
    bool act = (lane < 32);                    // C rows 0..7 = 2 nodes x 4 b
    long ne = (long)(q0 + (lane >> 4));        // valid only for act lanes
    const float4* xg4 = reinterpret_cast<const float4*>(g_xg);
    const short8 zero8 = {0, 0, 0, 0, 0, 0, 0, 0};

#pragma unroll
    for (int half = 0; half < 2; half++) {
        float4v c[4];
#pragma unroll
        for (int i = 0; i < 4; i++) c[i] = (float4v){0.f, 0.f, 0.f, 0.f};
#pragma unroll
        for (int kb = 0; kb < 4; kb++) {
            short8 af = zero8;
            if (arow < 8)                      // rows 8-15 of A are zero
                af = *reinterpret_cast<const short8*>(
                    &Atile[w][arow][kb * 32 + agrp * 8]);
#pragma unroll
            for (int tnn = 0; tnn < 4; tnn++) {
                int tn = half * 4 + tnn;
                short8 bf = *reinterpret_cast<const short8*>(
                    &g_wgB[((tn * 4 + kb) * 64 + lane) * 8]);
                c[tnn] = __builtin_amdgcn_mfma_f32_16x16x32_bf16(af, bf, c[tnn], 0, 0, 0);
            }
        }
        if (act) {
#pragma unroll
            for (int tnn = 0; tnn < 4; tnn++) {
                int h = (half * 4 + tnn) * 16 + hl;
                float bgh = bg[h];
#pragma unroll
                for (int jj = 0; jj < 4; jj++) {
                    long idx = (long)jj * stride + ne * H + h;
                    float cpv = __builtin_nontemporal_load(&c_prev[idx]);
                    float gh = c[tnn][jj] + bgh;
                    float4 xv = xg4[jj * H + h];   // {xi, xf, xo, xc}

                    float it = fast_sigmoid(xv.x + gh);
                    float ft = fast_sigmoid(xv.y + gh);
                    float ot = fast_sigmoid(xv.z + gh);
                    float ct = fast_tanh(xv.w + gh);

                    float cc = ft * cpv + it * ct;
                    float ho = ot * fast_tanh(cc);

                    __builtin_nontemporal_store(ho, &out_h[idx]);
                    __builtin_nontemporal_store(cc, &out_c[idx]);
                }
            }
        }
    }

    // own-node counter zeroing (fused reads only its own nodes' counters)
    if (lane < 2) {
        g_cnt_dst[q0 + lane] = 0;
        g_deg_src[q0 + lane] = 0;
    }
}

extern "C" void kernel_launch(void* const* d_in, const int* in_sizes, int n_in,
                              void* d_out, int out_size, void* d_ws, size_t ws_size,
                              hipStream_t stream) {
    const float* x      = (const float*)d_in[0];
    const float* h_prev = (const float*)d_in[1];
    const float* c_prev = (const float*)d_in[2];
    const int* src = (const int*)d_in[3];
    const int* dst = (const int*)d_in[4];
    const float* Wi = (const float*)d_in[5];
    const float* bi = (const float*)d_in[6];
    const float* Wf = (const float*)d_in[7];
    const float* bf_ = (const float*)d_in[8];
    const float* Wo = (const float*)d_in[9];
    const float* bo = (const float*)d_in[10];
    const float* Wc = (const float*)d_in[11];
    const float* bc = (const float*)d_in[12];
    const float* Wg = (const float*)d_in[13];
    const float* bg = (const float*)d_in[14];

    int E = in_sizes[3];
    if (E > E_MAX) E = E_MAX;   // static scratch bound (setup fixes E=320000)
    int eb = (E + 255) / 256;
    const int PACK_BLKS = (N_NODES * H) / 256;   // 10000

    degree_kernel<<<eb + 8 + 64, 256, 0, stream>>>(src, E, eb,
        x, Wi, bi, Wf, bf_, Wo, bo, Wc, bc, Wg);
    mid_kernel<<<PACK_BLKS + eb, 256, 0, stream>>>(h_prev, src, dst, E);

    float* out_h = (float*)d_out;
    float* out_c = out_h + (long)B * N_NODES * H;
    // 2500 blocks x 4 waves x 2 nodes = 20000 nodes
    fused_kernel<<<N_NODES / 8, 256, 0, stream>>>(bg, c_prev, out_h, out_c);
}

// Round 10
// 261.206 us; speedup vs baseline: 1.1465x; 1.1465x over previous
//
#include <hip/hip_runtime.h>
#include <hip/hip_bf16.h>

#define N_NODES 20000
#define B 4
#define H 128
#define I_DIM 64
#define E_MAX 320000
#define CAP 64              // padded CSR row capacity (in-deg ~Poisson(16); P(>63) ~ e^-40)

typedef __attribute__((ext_vector_type(8))) short short8;   // 8 bf16 = 4 VGPR (MFMA A/B frag)
typedef __attribute__((ext_vector_type(4))) float float4v;  // MFMA C/D frag

// ---- all scratch in module-static device globals (no d_ws dependence) ----
// g_cnt_dst / g_deg_src zeroed by fused_kernel (own-node only, post-use).
__device__ int   g_cnt_dst[N_NODES];        // atomic cursor == final in-degree
__device__ int   g_deg_src[N_NODES];        // out-degree
__device__ int   g_csr[N_NODES * CAP];      // padded CSR: row n at n*CAP
__device__ __align__(16) float g_xg[4 * B * H];   // layout: [(b*H+h)*4 + gate]
// batch-interleaved bf16 h_prev, PRE-SCALED by dn_src: g_hs[n*H+h]={bf16 h*dn, b=0..3}
__device__ __align__(16) uint2 g_hs[N_NODES * H];
// Wg as bf16 in MFMA B-fragment order (verified by R7 pass):
// idx=((tn*4+kb)*64+lane)*8+j holds Wg[kb*32+(lane>>4)*8+j][tn*16+(lane&15)]
__device__ __align__(16) unsigned short g_wgB[H * H];

// ---- K1: src-degree histogram + xgate + Wg bf16 B-frag pack ----
__global__ __launch_bounds__(256)
void degree_kernel(const int* __restrict__ src, int E, int eb,
                   const float* __restrict__ x,
                   const float* __restrict__ Wi, const float* __restrict__ bi,
                   const float* __restrict__ Wf, const float* __restrict__ bf_,
                   const float* __restrict__ Wo, const float* __restrict__ bo,
                   const float* __restrict__ Wc, const float* __restrict__ bc,
                   const float* __restrict__ Wg) {
    int blk = blockIdx.x;
    int t = threadIdx.x;
    if (blk < eb) {
        int e = blk * 256 + t;
        if (e < E) atomicAdd(&g_deg_src[src[e]], 1);
    } else if (blk < eb + 8) {
        int bid = blk - eb;                       // 0..7
        int g = bid >> 1;                         // gate 0..3
        int b = ((bid & 1) << 1) | (t >> 7);      // batch 0..3
        int h = t & 127;
        const float* W;
        const float* bb;
        switch (g) {
            case 0: W = Wi; bb = bi; break;
            case 1: W = Wf; bb = bf_; break;
            case 2: W = Wo; bb = bo; break;
            default: W = Wc; bb = bc; break;
        }
        float acc = bb[h];
#pragma unroll
        for (int i = 0; i < I_DIM; i++)
            acc += x[b * I_DIM + i] * W[i * H + h];
        g_xg[(b * H + h) * 4 + g] = acc;          // gate-innermost for float4 read
    } else {
        // B-fragment pack: 64 blocks x 256 threads = 16384 = H*H elements
        int i = (blk - eb - 8) * 256 + t;
        int tn = i >> 11;
        int rem = i & 2047;
        int kb = rem >> 9;
        int rem2 = rem & 511;
        int lane = rem2 >> 3;
        int j = rem2 & 7;
        int k  = kb * 32 + (lane >> 4) * 8 + j;
        int nn = tn * 16 + (lane & 15);
        __hip_bfloat16 hv = __float2bfloat16(Wg[k * H + nn]);
        g_wgB[i] = *reinterpret_cast<unsigned short*>(&hv);
    }
}

// ---- K2: pack (dn_src folded into bf16) + padded-CSR place ----
__global__ __launch_bounds__(256)
void mid_kernel(const float* __restrict__ h_prev,
                const int* __restrict__ src, const int* __restrict__ dst, int E) {
    const int PACK_BLKS = (N_NODES * H) / 256;   // 10000, exact
    int blk = blockIdx.x;
    int t = threadIdx.x;

    if (blk < PACK_BLKS) {
        int i = blk * 256 + t;                    // (n*H + h)
        int n = i >> 7;                           // H = 128
        float sc = rsqrtf(fmaxf((float)g_deg_src[n], 1.0f));
        const long stride = (long)N_NODES * H;
        float v0 = h_prev[i] * sc;
        float v1 = h_prev[i + stride] * sc;
        float v2 = h_prev[i + 2 * stride] * sc;
        float v3 = h_prev[i + 3 * stride] * sc;
        __hip_bfloat162 p01 = __float22bfloat162_rn(make_float2(v0, v1));
        __hip_bfloat162 p23 = __float22bfloat162_rn(make_float2(v2, v3));
        uint2 wv;
        wv.x = *reinterpret_cast<unsigned int*>(&p01);
        wv.y = *reinterpret_cast<unsigned int*>(&p23);
        g_hs[i] = wv;
    } else {
        int e = (blk - PACK_BLKS) * 256 + t;
        if (e < E) {
            int d = dst[e];
            int slot = atomicAdd(&g_cnt_dst[d], 1);
            if (slot < CAP) g_csr[(d << 6) + slot] = src[e];
        }
    }
}

__device__ __forceinline__ float fast_sigmoid(float z) {
    return 1.f / (1.f + __expf(-z));
}
__device__ __forceinline__ float fast_tanh(float z) {
    return 1.f - 2.f / (__expf(2.f * z) + 1.f);
}
__device__ __forceinline__ unsigned pack2bf(float lo, float hi) {
    __hip_bfloat162 p = __float22bfloat162_rn(make_float2(lo, hi));
    return *reinterpret_cast<unsigned*>(&p);
}

// ------- K3 fused: 1 node/WAVE (max gather parallelism, R7's law), ZERO ------
// barriers. A-tile rows replicated 4x (row r <-> batch r&3) so every C
// row-group is valid; wave runs all 8 N-tiles itself (MFMA is ~1% utilized,
// waste is free). Lane (g=lane>>4, col=lane&15) keeps tile tn=4*half+g ->
// h = 64*half + lane: full-lane epilogue, 256B-contiguous stores.
__global__ __launch_bounds__(256)
void fused_kernel(const float* __restrict__ bg,
                  const float* __restrict__ c_prev,
                  float* __restrict__ out_h, float* __restrict__ out_c) {
    int t = threadIdx.x;
    int w = t >> 6;
    int lane = t & 63;
    int n = (blockIdx.x << 2) + w;             // wave's own node
    const long stride = (long)N_NODES * H;

    __shared__ int            sbase[4][64];           // wave-private row bases
    __shared__ unsigned short Atile[4][16][136];      // wave-private, replicated

    int cnt = g_cnt_dst[n];                    // own-node counter: race-free
    float dd = rsqrtf(fmaxf((float)cnt, 1.0f));
    if (cnt > CAP) cnt = CAP;

    sbase[w][lane] = g_csr[(n << 6) + (lane < cnt ? lane : 0)] << 6;  // uint4 units

    // c_prev prefetch (nontemporal, read-once): h = 64*half + lane.
    // Latency rides under the gather; waited at epilogue use only.
    float cpr[2][4];
#pragma unroll
    for (int half = 0; half < 2; half++)
#pragma unroll
        for (int jj = 0; jj < 4; jj++)
            cpr[half][jj] = __builtin_nontemporal_load(
                &c_prev[(long)jj * stride + (long)n * H + 64 * half + lane]);

    // ---- gather (R7 structure verbatim): 8-wide uint4 MLP ----
    float a0 = 0.f, a1 = 0.f, a2 = 0.f, a3 = 0.f;   // h0 = 2*lane,   b0..b3
    float a4 = 0.f, a5 = 0.f, a6 = 0.f, a7 = 0.f;   // h1 = 2*lane+1, b0..b3
    const uint4* hs4 = reinterpret_cast<const uint4*>(g_hs);
    const int* sb = sbase[w];

#define ACCV(v) { \
        __hip_bfloat162 p; float2 f; \
        p = *reinterpret_cast<__hip_bfloat162*>(&(v).x); f = __bfloat1622float2(p); a0 += f.x; a1 += f.y; \
        p = *reinterpret_cast<__hip_bfloat162*>(&(v).y); f = __bfloat1622float2(p); a2 += f.x; a3 += f.y; \
        p = *reinterpret_cast<__hip_bfloat162*>(&(v).z); f = __bfloat1622float2(p); a4 += f.x; a5 += f.y; \
        p = *reinterpret_cast<__hip_bfloat162*>(&(v).w); f = __bfloat1622float2(p); a6 += f.x; a7 += f.y; }

    int j = 0;
    for (; j + 8 <= cnt; j += 8) {
        int b0 = sb[j];     int b1 = sb[j + 1];
        int b2 = sb[j + 2]; int b3 = sb[j + 3];
        int b4 = sb[j + 4]; int b5 = sb[j + 5];
        int b6 = sb[j + 6]; int b7 = sb[j + 7];
        uint4 v0 = hs4[b0 + lane]; uint4 v1 = hs4[b1 + lane];
        uint4 v2 = hs4[b2 + lane]; uint4 v3 = hs4[b3 + lane];
        uint4 v4 = hs4[b4 + lane]; uint4 v5 = hs4[b5 + lane];
        uint4 v6 = hs4[b6 + lane]; uint4 v7 = hs4[b7 + lane];
        ACCV(v0); ACCV(v1); ACCV(v2); ACCV(v3);
        ACCV(v4); ACCV(v5); ACCV(v6); ACCV(v7);
    }
    for (; j + 4 <= cnt; j += 4) {
        int b0 = sb[j];     int b1 = sb[j + 1];
        int b2 = sb[j + 2]; int b3 = sb[j + 3];
        uint4 v0 = hs4[b0 + lane]; uint4 v1 = hs4[b1 + lane];
        uint4 v2 = hs4[b2 + lane]; uint4 v3 = hs4[b3 + lane];
        ACCV(v0); ACCV(v1); ACCV(v2); ACCV(v3);
    }
    for (; j < cnt; j++) {
        uint4 v = hs4[sb[j] + lane];
        ACCV(v);
    }
#undef ACCV

    // ---- write replicated A rows (wave-private; same-wave lgkmcnt orders
    //      these against the frag reads below -- no barrier) ----
    unsigned p0 = pack2bf(a0 * dd, a4 * dd);   // batch 0: (h0, h1)
    unsigned p1 = pack2bf(a1 * dd, a5 * dd);
    unsigned p2 = pack2bf(a2 * dd, a6 * dd);
    unsigned p3 = pack2bf(a3 * dd, a7 * dd);
#pragma unroll
    for (int r = 0; r < 16; r++) {
        unsigned pv = ((r & 3) == 0) ? p0 : ((r & 3) == 1) ? p1
                    : ((r & 3) == 2) ? p2 : p3;
        *reinterpret_cast<unsigned*>(&Atile[w][r][2 * lane]) = pv;
    }

    // ---- MFMA + epilogue, two halves of 4 N-tiles (c[4] live = 16 regs) ----
    int arow = lane & 15;
    int agrp = lane >> 4;
    int g = lane >> 4;
    const float4* xg4 = reinterpret_cast<const float4*>(g_xg);

#pragma unroll
    for (int half = 0; half < 2; half++) {
        float4v c0 = {0.f, 0.f, 0.f, 0.f};
        float4v c1 = {0.f, 0.f, 0.f, 0.f};
        float4v c2 = {0.f, 0.f, 0.f, 0.f};
        float4v c3 = {0.f, 0.f, 0.f, 0.f};
#pragma unroll
        for (int kb = 0; kb < 4; kb++) {
            short8 af = *reinterpret_cast<const short8*>(
                &Atile[w][arow][kb * 32 + agrp * 8]);
            short8 b0 = *reinterpret_cast<const short8*>(
                &g_wgB[(((4 * half + 0) * 4 + kb) * 64 + lane) * 8]);
            short8 b1 = *reinterpret_cast<const short8*>(
                &g_wgB[(((4 * half + 1) * 4 + kb) * 64 + lane) * 8]);
            short8 b2 = *reinterpret_cast<const short8*>(
                &g_wgB[(((4 * half + 2) * 4 + kb) * 64 + lane) * 8]);
            short8 b3 = *reinterpret_cast<const short8*>(
                &g_wgB[(((4 * half + 3) * 4 + kb) * 64 + lane) * 8]);
            c0 = __builtin_amdgcn_mfma_f32_16x16x32_bf16(af, b0, c0, 0, 0, 0);
            c1 = __builtin_amdgcn_mfma_f32_16x16x32_bf16(af, b1, c1, 0, 0, 0);
            c2 = __builtin_amdgcn_mfma_f32_16x16x32_bf16(af, b2, c2, 0, 0, 0);
            c3 = __builtin_amdgcn_mfma_f32_16x16x32_bf16(af, b3, c3, 0, 0, 0);
        }
        // lane keeps tile tn = 4*half + g; its C rows 4g+jj = batch jj.
        // Static cndmask select (no runtime reg-array index -> no scratch).
        float4v mine = (g == 0) ? c0 : (g == 1) ? c1 : (g == 2) ? c2 : c3;

        int h = 64 * half + lane;              // == (4*half+g)*16 + (lane&15)
        float bgh = bg[h];
#pragma unroll
        for (int jj = 0; jj < 4; jj++) {
            float gh = mine[jj] + bgh;
            float4 xv = xg4[jj * H + h];       // {xi, xf, xo, xc}

            float it = fast_sigmoid(xv.x + gh);
            float ft = fast_sigmoid(xv.y + gh);
            float ot = fast_sigmoid(xv.z + gh);
            float ct = fast_tanh(xv.w + gh);

            float cc = ft * cpr[half][jj] + it * ct;
            float ho = ot * fast_tanh(cc);

            long idx = (long)jj * stride + (long)n * H + h;
            __builtin_nontemporal_store(ho, &out_h[idx]);
            __builtin_nontemporal_store(cc, &out_c[idx]);
        }
    }

    // own-node counter zeroing (fused reads only its own node's counter)
    if (lane == 0) g_cnt_dst[n] = 0;
    if (lane == 1) g_deg_src[n] = 0;
}

extern "C" void kernel_launch(void* const* d_in, const int* in_sizes, int n_in,
                              void* d_out, int out_size, void* d_ws, size_t ws_size,
                              hipStream_t stream) {
    const float* x      = (const float*)d_in[0];
    const float* h_prev = (const float*)d_in[1];
    const float* c_prev = (const float*)d_in[2];
    const int* src = (const int*)d_in[3];
    const int* dst = (const int*)d_in[4];
    const float* Wi = (const float*)d_in[5];
    const float* bi = (const float*)d_in[6];
    const float* Wf = (const float*)d_in[7];
    const float* bf_ = (const float*)d_in[8];
    const float* Wo = (const float*)d_in[9];
    const float* bo = (const float*)d_in[10];
    const float* Wc = (const float*)d_in[11];
    const float* bc = (const float*)d_in[12];
    const float* Wg = (const float*)d_in[13];
    const float* bg = (const float*)d_in[14];

    int E = in_sizes[3];
    if (E > E_MAX) E = E_MAX;   // static scratch bound (setup fixes E=320000)
    int eb = (E + 255) / 256;
    const int PACK_BLKS = (N_NODES * H) / 256;   // 10000

    degree_kernel<<<eb + 8 + 64, 256, 0, stream>>>(src, E, eb,
        x, Wi, bi, Wf, bf_, Wo, bo, Wc, bc, Wg);
    mid_kernel<<<PACK_BLKS + eb, 256, 0, stream>>>(h_prev, src, dst, E);

    float* out_h = (float*)d_out;
    float* out_c = out_h + (long)B * N_NODES * H;
    // 5000 blocks x 4 waves x 1 node/wave = 20000 nodes
    fused_kernel<<<N_NODES / 4, 256, 0, stream>>>(bg, c_prev, out_h, out_c);
}